// Round 8
// baseline (482.670 us; speedup 1.0000x reference)
//
#include <hip/hip_runtime.h>

#define NN 50000
#define MPAD 50048      // NN rounded up to BM
#define HD 8
#define CD 64
#define NHF 512   // HD*CD
#define SCAN_B 256
#define NBLK ((NN + SCAN_B - 1) / SCAN_B)   // 196

typedef __attribute__((ext_vector_type(8))) short short8v;
typedef __attribute__((ext_vector_type(8))) unsigned short us8;
typedef __attribute__((ext_vector_type(4))) unsigned short us4;
typedef __attribute__((ext_vector_type(4))) float f32x4;
typedef __attribute__((ext_vector_type(8))) _Float16 h8;

__device__ inline unsigned short f32_to_bf16(float f) {
    unsigned int u = __float_as_uint(f);
    unsigned int r = (u + 0x7fffu + ((u >> 16) & 1u)) >> 16;
    return (unsigned short)r;
}
__device__ inline float bf16_to_f32(unsigned short h) {
    return __uint_as_float(((unsigned int)h) << 16);
}

// ---------------- CSR build (by destination) ----------------
__global__ void k_init_cnt(int* __restrict__ cnt) {
    int i = blockIdx.x * 256 + threadIdx.x;
    if (i < NN) cnt[i] = 1;  // self loop contributes 1 per node
}

__global__ void k_hist(const int* __restrict__ dst, int E, int* __restrict__ cnt) {
    int e = blockIdx.x * 256 + threadIdx.x;
    if (e < E) atomicAdd(&cnt[dst[e]], 1);
}

__global__ __launch_bounds__(SCAN_B) void k_block_sums(const int* __restrict__ cnt,
                                                       int* __restrict__ bsums) {
    __shared__ int sdata[4];
    int i = blockIdx.x * SCAN_B + threadIdx.x;
    int v = (i < NN) ? cnt[i] : 0;
#pragma unroll
    for (int off = 1; off < 64; off <<= 1) v += __shfl_xor(v, off);
    if ((threadIdx.x & 63) == 0) sdata[threadIdx.x >> 6] = v;
    __syncthreads();
    if (threadIdx.x == 0) bsums[blockIdx.x] = sdata[0] + sdata[1] + sdata[2] + sdata[3];
}

__global__ __launch_bounds__(SCAN_B) void k_scan_bsums(const int* __restrict__ bsums,
                                                       int* __restrict__ boffs, int nblk) {
    __shared__ int tmp[SCAN_B];
    int tid = threadIdx.x;
    int v = (tid < nblk) ? bsums[tid] : 0;
    tmp[tid] = v;
    __syncthreads();
    for (int off = 1; off < SCAN_B; off <<= 1) {
        int t = (tid >= off) ? tmp[tid - off] : 0;
        __syncthreads();
        tmp[tid] += t;
        __syncthreads();
    }
    if (tid < nblk) boffs[tid] = tmp[tid] - v;   // exclusive
}

// cnt and cursor alias: each index read/written only by its owning thread.
__global__ __launch_bounds__(SCAN_B) void k_emit(const int* __restrict__ cnt,
                                                 const int* __restrict__ boffs,
                                                 int* __restrict__ row_ptr,
                                                 int* __restrict__ cursor,
                                                 int* __restrict__ csr_src) {
    __shared__ int tmp[SCAN_B];
    int tid = threadIdx.x;
    int i = blockIdx.x * SCAN_B + tid;
    int v = (i < NN) ? cnt[i] : 0;
    tmp[tid] = v;
    __syncthreads();
    for (int off = 1; off < SCAN_B; off <<= 1) {
        int t = (tid >= off) ? tmp[tid - off] : 0;
        __syncthreads();
        tmp[tid] += t;
        __syncthreads();
    }
    int base = boffs[blockIdx.x] + tmp[tid] - v;  // exclusive prefix
    if (i < NN) {
        row_ptr[i] = base;
        csr_src[base] = i;      // self-loop first in each segment
        cursor[i] = base + 1;
        if (i == NN - 1) row_ptr[NN] = base + v;  // = E + NN
    }
}

__global__ void k_scatter(const int* __restrict__ src, const int* __restrict__ dst,
                          int E, int* __restrict__ cursor, int* __restrict__ csr_src) {
    int e = blockIdx.x * 256 + threadIdx.x;
    if (e < E) {
        int pos = atomicAdd(&cursor[dst[e]], 1);
        csr_src[pos] = src[e];
    }
}

// ---------------- weight split+transpose: B[K][512] -> Bt_hi/lo [512][K] bf16 ----------------
__global__ void k_split_bt(const float* __restrict__ B, unsigned short* __restrict__ bht,
                           unsigned short* __restrict__ blt, int K) {
    int idx = blockIdx.x * 256 + threadIdx.x;
    if (idx < K * NHF) {
        int k = idx >> 9, n = idx & 511;
        float v = B[idx];
        unsigned short hb = f32_to_bf16(v);
        float l = v - bf16_to_f32(hb);
        blt[n * K + k] = f32_to_bf16(l);
        bht[n * K + k] = hb;
    }
}

// ---------------- A split: f32 [M][K] -> bf16 hi/lo [MPAD][K] (pad rows zeroed) --------------
__global__ void k_split_a(const float* __restrict__ A, unsigned short* __restrict__ ah,
                          unsigned short* __restrict__ al, int M, int K) {
    int idx = blockIdx.x * 256 + threadIdx.x;   // float4 index
    int tot = (MPAD * K) >> 2;
    if (idx >= tot) return;
    int row = (idx << 2) / K;
    float4 v = make_float4(0.f, 0.f, 0.f, 0.f);
    if (row < M) v = *(const float4*)(A + ((size_t)idx << 2));
    us4 hs, ls;
    hs.x = f32_to_bf16(v.x); ls.x = f32_to_bf16(v.x - bf16_to_f32(hs.x));
    hs.y = f32_to_bf16(v.y); ls.y = f32_to_bf16(v.y - bf16_to_f32(hs.y));
    hs.z = f32_to_bf16(v.z); ls.z = f32_to_bf16(v.z - bf16_to_f32(hs.z));
    hs.w = f32_to_bf16(v.w); ls.w = f32_to_bf16(v.w - bf16_to_f32(hs.w));
    *(us4*)(ah + ((size_t)idx << 2)) = hs;
    *(us4*)(al + ((size_t)idx << 2)) = ls;
}

// ---------------- split-bf16 MFMA GEMM + fused alpha epilogue ----------------
// All operands pre-split bf16 -> staging is pure 16B vector loads, branch-free.
#define BM 128
#define BN 128
#define BKF 32
#define LDK 40   // padded LDS row stride in ushort (80 B)

__global__ __launch_bounds__(256) void k_gemm_mfma(
    const unsigned short* __restrict__ Aht,  // [MPAD][K] bf16
    const unsigned short* __restrict__ Alt,
    const unsigned short* __restrict__ Bht,  // [512][K] bf16 (n-major)
    const unsigned short* __restrict__ Blt,
    const float* __restrict__ a_src, const float* __restrict__ a_dst,
    _Float16* __restrict__ C, float* __restrict__ asrc_out, float* __restrict__ adst_out,
    int M, int K)
{
    __shared__ unsigned short Ash[BM][LDK];
    __shared__ unsigned short Asl[BM][LDK];
    __shared__ unsigned short Bsh[BN][LDK];
    __shared__ unsigned short Bsl[BN][LDK];

    const int t = threadIdx.x;
    const int lane = t & 63;
    const int wid = t >> 6;
    const int wr = wid >> 1, wc = wid & 1;
    const int bm = blockIdx.x * BM;
    const int bn = blockIdx.y * BN;
    const int l15 = lane & 15;
    const int lg = lane >> 4;

    f32x4 acc[4][4];
#pragma unroll
    for (int mi = 0; mi < 4; ++mi)
#pragma unroll
        for (int ni = 0; ni < 4; ++ni)
            acc[mi][ni] = (f32x4){0.f, 0.f, 0.f, 0.f};

    const int srow = t >> 1;
    const int skc = (t & 1) * 16;

    for (int k0 = 0; k0 < K; k0 += BKF) {
        __syncthreads();
        {
            const unsigned short* gah = Aht + (size_t)(bm + srow) * K + k0 + skc;
            const unsigned short* gal = Alt + (size_t)(bm + srow) * K + k0 + skc;
            const unsigned short* gbh = Bht + (size_t)(bn + srow) * K + k0 + skc;
            const unsigned short* gbl = Blt + (size_t)(bn + srow) * K + k0 + skc;
            *(us8*)&Ash[srow][skc]     = *(const us8*)gah;
            *(us8*)&Ash[srow][skc + 8] = *(const us8*)(gah + 8);
            *(us8*)&Asl[srow][skc]     = *(const us8*)gal;
            *(us8*)&Asl[srow][skc + 8] = *(const us8*)(gal + 8);
            *(us8*)&Bsh[srow][skc]     = *(const us8*)gbh;
            *(us8*)&Bsh[srow][skc + 8] = *(const us8*)(gbh + 8);
            *(us8*)&Bsl[srow][skc]     = *(const us8*)gbl;
            *(us8*)&Bsl[srow][skc + 8] = *(const us8*)(gbl + 8);
        }
        __syncthreads();

        short8v ah[4], al[4], bh[4], bl[4];
#pragma unroll
        for (int i = 0; i < 4; ++i) {
            ah[i] = *(const short8v*)&Ash[wr * 64 + i * 16 + l15][lg * 8];
            al[i] = *(const short8v*)&Asl[wr * 64 + i * 16 + l15][lg * 8];
            bh[i] = *(const short8v*)&Bsh[wc * 64 + i * 16 + l15][lg * 8];
            bl[i] = *(const short8v*)&Bsl[wc * 64 + i * 16 + l15][lg * 8];
        }
#pragma unroll
        for (int mi = 0; mi < 4; ++mi)
#pragma unroll
            for (int ni = 0; ni < 4; ++ni) {
                acc[mi][ni] = __builtin_amdgcn_mfma_f32_16x16x32_bf16(ah[mi], bh[ni], acc[mi][ni], 0, 0, 0);
                acc[mi][ni] = __builtin_amdgcn_mfma_f32_16x16x32_bf16(ah[mi], bl[ni], acc[mi][ni], 0, 0, 0);
                acc[mi][ni] = __builtin_amdgcn_mfma_f32_16x16x32_bf16(al[mi], bh[ni], acc[mi][ni], 0, 0, 0);
            }
    }

    const int head_w = (bn >> 6) + wc;
    float ca[4], cd[4];
#pragma unroll
    for (int ni = 0; ni < 4; ++ni) {
        ca[ni] = a_src[head_w * 64 + ni * 16 + l15];
        cd[ni] = a_dst[head_w * 64 + ni * 16 + l15];
    }
#pragma unroll
    for (int mi = 0; mi < 4; ++mi) {
#pragma unroll
        for (int r = 0; r < 4; ++r) {
            int row = bm + wr * 64 + mi * 16 + lg * 4 + r;
            float ps = 0.f, pd = 0.f;
#pragma unroll
            for (int ni = 0; ni < 4; ++ni) {
                float cv = acc[mi][ni][r];
                int col = bn + wc * 64 + ni * 16 + l15;
                if (row < M) C[(size_t)row * NHF + col] = (_Float16)cv;
                ps += cv * ca[ni];
                pd += cv * cd[ni];
            }
#pragma unroll
            for (int off = 1; off < 16; off <<= 1) {
                ps += __shfl_xor(ps, off);
                pd += __shfl_xor(pd, off);
            }
            if (l15 == 0 && row < M) {
                asrc_out[row * HD + head_w] = ps;
                adst_out[row * HD + head_w] = pd;
            }
        }
    }
}

// ---------------- fused edge softmax + aggregation ----------------
// ONE wave per node: each lane owns 8 contiguous feats (16B h8 load per edge).
// 4-edge batches (64B/lane in flight). Direct exp (max cancels; alphas bounded).
// Layer 1 (mode=1): ReLU + write h as bf16 hi/lo (pre-split for GEMM2).
// Layer 2 (mode=0): write f32 to out.
__global__ __launch_bounds__(256) void k_aggregate(
    const _Float16* __restrict__ xl, const float* __restrict__ asrc,
    const float* __restrict__ adst, const int* __restrict__ row_ptr,
    const int* __restrict__ csr_src, const float* __restrict__ bias,
    float* __restrict__ out, unsigned short* __restrict__ o_hi,
    unsigned short* __restrict__ o_lo, int mode)
{
    __shared__ float sh[4][NHF];
    const int wid  = threadIdx.x >> 6;
    const int lane = threadIdx.x & 63;
    const int n    = blockIdx.x * 4 + wid;   // NN % 4 == 0
    const int head = lane >> 3;
    const int off  = lane * 8;

    const float ad = adst[n * HD + head];
    const int e0 = row_ptr[n];
    const int e1 = row_ptr[n + 1];

    float acc[8] = {};
    float s = 0.f;

    int e = e0;
    for (; e + 4 <= e1; e += 4) {
        int i0 = csr_src[e];
        int i1 = csr_src[e + 1];
        int i2 = csr_src[e + 2];
        int i3 = csr_src[e + 3];
        float a0 = asrc[i0 * HD + head];
        float a1 = asrc[i1 * HD + head];
        float a2 = asrc[i2 * HD + head];
        float a3 = asrc[i3 * HD + head];
        h8 v0 = *(const h8*)(xl + (size_t)i0 * NHF + off);
        h8 v1 = *(const h8*)(xl + (size_t)i1 * NHF + off);
        h8 v2 = *(const h8*)(xl + (size_t)i2 * NHF + off);
        h8 v3 = *(const h8*)(xl + (size_t)i3 * NHF + off);
        a0 += ad; a1 += ad; a2 += ad; a3 += ad;
        float p0 = __expf(a0 > 0.f ? a0 : 0.2f * a0);
        float p1 = __expf(a1 > 0.f ? a1 : 0.2f * a1);
        float p2 = __expf(a2 > 0.f ? a2 : 0.2f * a2);
        float p3 = __expf(a3 > 0.f ? a3 : 0.2f * a3);
        s += p0 + p1 + p2 + p3;
#pragma unroll
        for (int j = 0; j < 8; ++j) {
            acc[j] += p0 * (float)v0[j];
            acc[j] += p1 * (float)v1[j];
            acc[j] += p2 * (float)v2[j];
            acc[j] += p3 * (float)v3[j];
        }
    }
    for (; e < e1; ++e) {
        int i0 = csr_src[e];
        float a = asrc[i0 * HD + head] + ad;
        h8 vv = *(const h8*)(xl + (size_t)i0 * NHF + off);
        float p = __expf(a > 0.f ? a : 0.2f * a);
        s += p;
#pragma unroll
        for (int j = 0; j < 8; ++j) acc[j] += p * (float)vv[j];
    }

    const float inv = 1.f / (s + 1e-16f);
#pragma unroll
    for (int j = 0; j < 8; ++j) sh[wid][off + j] = acc[j] * inv;
    __syncthreads();

    float sum = 0.f;
#pragma unroll
    for (int h2 = 0; h2 < HD; ++h2) sum += sh[wid][h2 * CD + lane];
    float res = sum * 0.125f + bias[lane];
    if (mode) {
        res = fmaxf(res, 0.f);
        unsigned short hb = f32_to_bf16(res);
        o_hi[(size_t)n * CD + lane] = hb;
        o_lo[(size_t)n * CD + lane] = f32_to_bf16(res - bf16_to_f32(hb));
    } else {
        out[(size_t)n * CD + lane] = res;
    }
}

// ---------------- launch ----------------
extern "C" void kernel_launch(void* const* d_in, const int* in_sizes, int n_in,
                              void* d_out, int out_size, void* d_ws, size_t ws_size,
                              hipStream_t stream) {
    const float* x   = (const float*)d_in[0];
    const int*   ei  = (const int*)d_in[1];
    const float* W1  = (const float*)d_in[2];
    const float* as1 = (const float*)d_in[3];
    const float* ad1 = (const float*)d_in[4];
    const float* b1  = (const float*)d_in[5];
    const float* W2  = (const float*)d_in[6];
    const float* as2 = (const float*)d_in[7];
    const float* ad2 = (const float*)d_in[8];
    const float* b2  = (const float*)d_in[9];

    const int E = in_sizes[1] / 2;      // 800000
    const int* esrc = ei;
    const int* edst = ei + E;

    char* ws = (char*)d_ws;
    _Float16* xlh        = (_Float16*)ws;                          // 51,200,000
    unsigned short* Ah1  = (unsigned short*)(ws + 51200000);       // 25,624,576 (MPAD*256*2)
    unsigned short* Al1  = (unsigned short*)(ws + 76824576);       // 25,624,576
    float* asrc          = (float*)(ws + 102449152);               // 1,600,000
    float* adst          = (float*)(ws + 104049152);               // 1,600,000
    unsigned short* Hh   = (unsigned short*)(ws + 105649152);      // 6,406,144 (MPAD*64*2)
    unsigned short* Hl   = (unsigned short*)(ws + 112055296);      // 6,406,144
    int*   row_ptr       = (int*)(ws + 118461440);                 // 200,004
    int*   cursor        = (int*)(ws + 118661632);                 // 200,000
    int*   csr_src       = (int*)(ws + 118861632);                 // 3,400,000
    unsigned short* Bht1 = (unsigned short*)(ws + 122261632);      // 262,144
    unsigned short* Blt1 = (unsigned short*)(ws + 122523776);      // 262,144
    unsigned short* Bht2 = (unsigned short*)(ws + 122785920);      // 65,536
    unsigned short* Blt2 = (unsigned short*)(ws + 122851456);      // 65,536
    int*   bsums         = (int*)(ws + 122916992);                 // 784
    int*   boffs         = (int*)(ws + 122917888);                 // 784

    // CSR build (shared by both layers)
    k_init_cnt<<<(NN + 255) / 256, 256, 0, stream>>>(cursor);
    k_hist<<<(E + 255) / 256, 256, 0, stream>>>(edst, E, cursor);
    k_block_sums<<<NBLK, SCAN_B, 0, stream>>>(cursor, bsums);
    k_scan_bsums<<<1, SCAN_B, 0, stream>>>(bsums, boffs, NBLK);
    k_emit<<<NBLK, SCAN_B, 0, stream>>>(cursor, boffs, row_ptr, cursor, csr_src);
    k_scatter<<<(E + 255) / 256, 256, 0, stream>>>(esrc, edst, E, cursor, csr_src);

    // weight + input splits
    k_split_bt<<<(256 * NHF + 255) / 256, 256, 0, stream>>>(W1, Bht1, Blt1, 256);
    k_split_bt<<<(64 * NHF + 255) / 256, 256, 0, stream>>>(W2, Bht2, Blt2, 64);
    k_split_a<<<((MPAD * 256 / 4) + 255) / 256, 256, 0, stream>>>(x, Ah1, Al1, NN, 256);

    dim3 gemm_grid(MPAD / BM, NHF / BN);

    // layer 1
    k_gemm_mfma<<<gemm_grid, 256, 0, stream>>>(Ah1, Al1, Bht1, Blt1, as1, ad1,
                                               xlh, asrc, adst, NN, 256);
    k_aggregate<<<NN / 4, 256, 0, stream>>>(xlh, asrc, adst, row_ptr, csr_src, b1,
                                            nullptr, Hh, Hl, 1);

    // layer 2 (h already split bf16 by aggregate-1)
    k_gemm_mfma<<<gemm_grid, 256, 0, stream>>>(Hh, Hl, Bht2, Blt2, as2, ad2,
                                               xlh, asrc, adst, NN, 64);
    k_aggregate<<<NN / 4, 256, 0, stream>>>(xlh, asrc, adst, row_ptr, csr_src, b2,
                                            (float*)d_out, nullptr, nullptr, 0);
}

// Round 9
// 452.005 us; speedup vs baseline: 1.0678x; 1.0678x over previous
//
#include <hip/hip_runtime.h>

#define NN 50000
#define MPAD 50048      // NN rounded up to BM
#define HD 8
#define CD 64
#define NHF 512   // HD*CD
#define SCAN_B 256
#define NBLK ((NN + SCAN_B - 1) / SCAN_B)   // 196

typedef __attribute__((ext_vector_type(8))) short short8v;
typedef __attribute__((ext_vector_type(8))) unsigned short us8;
typedef __attribute__((ext_vector_type(4))) unsigned short us4;
typedef __attribute__((ext_vector_type(4))) float f32x4;
typedef __attribute__((ext_vector_type(8))) _Float16 h8;

__device__ inline unsigned short f32_to_bf16(float f) {
    unsigned int u = __float_as_uint(f);
    unsigned int r = (u + 0x7fffu + ((u >> 16) & 1u)) >> 16;
    return (unsigned short)r;
}
__device__ inline float bf16_to_f32(unsigned short h) {
    return __uint_as_float(((unsigned int)h) << 16);
}

// ---------------- CSR build (by destination) ----------------
__global__ void k_init_cnt(int* __restrict__ cnt) {
    int i = blockIdx.x * 256 + threadIdx.x;
    if (i < NN) cnt[i] = 1;  // self loop contributes 1 per node
}

__global__ void k_hist(const int* __restrict__ dst, int E, int* __restrict__ cnt) {
    int e = blockIdx.x * 256 + threadIdx.x;
    if (e < E) atomicAdd(&cnt[dst[e]], 1);
}

__global__ __launch_bounds__(SCAN_B) void k_block_sums(const int* __restrict__ cnt,
                                                       int* __restrict__ bsums) {
    __shared__ int sdata[4];
    int i = blockIdx.x * SCAN_B + threadIdx.x;
    int v = (i < NN) ? cnt[i] : 0;
#pragma unroll
    for (int off = 1; off < 64; off <<= 1) v += __shfl_xor(v, off);
    if ((threadIdx.x & 63) == 0) sdata[threadIdx.x >> 6] = v;
    __syncthreads();
    if (threadIdx.x == 0) bsums[blockIdx.x] = sdata[0] + sdata[1] + sdata[2] + sdata[3];
}

__global__ __launch_bounds__(SCAN_B) void k_scan_bsums(const int* __restrict__ bsums,
                                                       int* __restrict__ boffs, int nblk) {
    __shared__ int tmp[SCAN_B];
    int tid = threadIdx.x;
    int v = (tid < nblk) ? bsums[tid] : 0;
    tmp[tid] = v;
    __syncthreads();
    for (int off = 1; off < SCAN_B; off <<= 1) {
        int t = (tid >= off) ? tmp[tid - off] : 0;
        __syncthreads();
        tmp[tid] += t;
        __syncthreads();
    }
    if (tid < nblk) boffs[tid] = tmp[tid] - v;   // exclusive
}

// cnt and cursor alias: each index read/written only by its owning thread.
__global__ __launch_bounds__(SCAN_B) void k_emit(const int* __restrict__ cnt,
                                                 const int* __restrict__ boffs,
                                                 int* __restrict__ row_ptr,
                                                 int* __restrict__ cursor,
                                                 int* __restrict__ csr_src) {
    __shared__ int tmp[SCAN_B];
    int tid = threadIdx.x;
    int i = blockIdx.x * SCAN_B + tid;
    int v = (i < NN) ? cnt[i] : 0;
    tmp[tid] = v;
    __syncthreads();
    for (int off = 1; off < SCAN_B; off <<= 1) {
        int t = (tid >= off) ? tmp[tid - off] : 0;
        __syncthreads();
        tmp[tid] += t;
        __syncthreads();
    }
    int base = boffs[blockIdx.x] + tmp[tid] - v;  // exclusive prefix
    if (i < NN) {
        row_ptr[i] = base;
        csr_src[base] = i;      // self-loop first in each segment
        cursor[i] = base + 1;
        if (i == NN - 1) row_ptr[NN] = base + v;  // = E + NN
    }
}

__global__ void k_scatter(const int* __restrict__ src, const int* __restrict__ dst,
                          int E, int* __restrict__ cursor, int* __restrict__ csr_src) {
    int e = blockIdx.x * 256 + threadIdx.x;
    if (e < E) {
        int pos = atomicAdd(&cursor[dst[e]], 1);
        csr_src[pos] = src[e];
    }
}

// ---------------- weight split+transpose: B[K][512] -> Bt_hi/lo [512][K] bf16 ----------------
__global__ void k_split_bt(const float* __restrict__ B, unsigned short* __restrict__ bht,
                           unsigned short* __restrict__ blt, int K) {
    int idx = blockIdx.x * 256 + threadIdx.x;
    if (idx < K * NHF) {
        int k = idx >> 9, n = idx & 511;
        float v = B[idx];
        unsigned short hb = f32_to_bf16(v);
        float l = v - bf16_to_f32(hb);
        blt[n * K + k] = f32_to_bf16(l);
        bht[n * K + k] = hb;
    }
}

// ---------------- split-bf16 MFMA GEMM + fused alpha epilogue ----------------
// BM=128, BN=256, 512 threads (8 waves, 2x4), wave tile 64x64.
// SPLIT=1: A is f32, hi/lo-split during LDS staging (layer 1: A = x).
// SPLIT=0: A is pre-split bf16 hi/lo (layer 2: A = h written by aggregate-1).
#define BM 128
#define BN 256
#define BKF 32
#define LDK 40   // padded LDS row stride in ushort (80 B)

template<int SPLIT>
__global__ __launch_bounds__(512) void k_gemm(
    const float* __restrict__ Af,            // SPLIT=1
    const unsigned short* __restrict__ Aht,  // SPLIT=0: [MPAD][K]
    const unsigned short* __restrict__ Alt,
    const unsigned short* __restrict__ Bht,  // [512][K] bf16 (n-major)
    const unsigned short* __restrict__ Blt,
    const float* __restrict__ a_src, const float* __restrict__ a_dst,
    _Float16* __restrict__ C, float* __restrict__ asrc_out, float* __restrict__ adst_out,
    int M, int K)
{
    __shared__ unsigned short Ash[BM][LDK];
    __shared__ unsigned short Asl[BM][LDK];
    __shared__ unsigned short Bsh[BN][LDK];
    __shared__ unsigned short Bsl[BN][LDK];

    const int t = threadIdx.x;
    const int lane = t & 63;
    const int wid = t >> 6;          // 0..7
    const int wr = wid >> 2;         // 0..1
    const int wc = wid & 3;          // 0..3
    const int bm = blockIdx.x * BM;
    const int bn = blockIdx.y * BN;
    const int l15 = lane & 15;
    const int lg = lane >> 4;

    f32x4 acc[4][4];
#pragma unroll
    for (int mi = 0; mi < 4; ++mi)
#pragma unroll
        for (int ni = 0; ni < 4; ++ni)
            acc[mi][ni] = (f32x4){0.f, 0.f, 0.f, 0.f};

    const int srowA = t >> 2;          // 0..127
    const int skcA  = (t & 3) * 8;     // 0,8,16,24
    const int srowB = t >> 1;          // 0..255
    const int skcB  = (t & 1) * 16;    // 0,16

    for (int k0 = 0; k0 < K; k0 += BKF) {
        __syncthreads();
        // ---- stage A ----
        if (SPLIT) {
            const int gr = bm + srowA;
            if (gr < M) {
                const float* ga = Af + (size_t)gr * K + k0 + skcA;
                float4 v0 = *(const float4*)ga;
                float4 v1 = *(const float4*)(ga + 4);
                us4 h0, l0, h1, l1;
                h0.x = f32_to_bf16(v0.x); l0.x = f32_to_bf16(v0.x - bf16_to_f32(h0.x));
                h0.y = f32_to_bf16(v0.y); l0.y = f32_to_bf16(v0.y - bf16_to_f32(h0.y));
                h0.z = f32_to_bf16(v0.z); l0.z = f32_to_bf16(v0.z - bf16_to_f32(h0.z));
                h0.w = f32_to_bf16(v0.w); l0.w = f32_to_bf16(v0.w - bf16_to_f32(h0.w));
                h1.x = f32_to_bf16(v1.x); l1.x = f32_to_bf16(v1.x - bf16_to_f32(h1.x));
                h1.y = f32_to_bf16(v1.y); l1.y = f32_to_bf16(v1.y - bf16_to_f32(h1.y));
                h1.z = f32_to_bf16(v1.z); l1.z = f32_to_bf16(v1.z - bf16_to_f32(h1.z));
                h1.w = f32_to_bf16(v1.w); l1.w = f32_to_bf16(v1.w - bf16_to_f32(h1.w));
                *(us4*)&Ash[srowA][skcA]     = h0;
                *(us4*)&Ash[srowA][skcA + 4] = h1;
                *(us4*)&Asl[srowA][skcA]     = l0;
                *(us4*)&Asl[srowA][skcA + 4] = l1;
            } else {
                us4 z = (us4){0, 0, 0, 0};
                *(us4*)&Ash[srowA][skcA]     = z;
                *(us4*)&Ash[srowA][skcA + 4] = z;
                *(us4*)&Asl[srowA][skcA]     = z;
                *(us4*)&Asl[srowA][skcA + 4] = z;
            }
        } else {
            // pre-split bf16 (MPAD-sized buffers; pad rows garbage but guarded at store)
            const unsigned short* gah = Aht + (size_t)(bm + srowA) * K + k0 + skcA;
            const unsigned short* gal = Alt + (size_t)(bm + srowA) * K + k0 + skcA;
            *(us8*)&Ash[srowA][skcA] = *(const us8*)gah;
            *(us8*)&Asl[srowA][skcA] = *(const us8*)gal;
        }
        // ---- stage B ----
        {
            const unsigned short* gbh = Bht + (size_t)(bn + srowB) * K + k0 + skcB;
            const unsigned short* gbl = Blt + (size_t)(bn + srowB) * K + k0 + skcB;
            *(us8*)&Bsh[srowB][skcB]     = *(const us8*)gbh;
            *(us8*)&Bsh[srowB][skcB + 8] = *(const us8*)(gbh + 8);
            *(us8*)&Bsl[srowB][skcB]     = *(const us8*)gbl;
            *(us8*)&Bsl[srowB][skcB + 8] = *(const us8*)(gbl + 8);
        }
        __syncthreads();

        short8v ah[4], al[4], bh[4], bl[4];
#pragma unroll
        for (int i = 0; i < 4; ++i) {
            ah[i] = *(const short8v*)&Ash[wr * 64 + i * 16 + l15][lg * 8];
            al[i] = *(const short8v*)&Asl[wr * 64 + i * 16 + l15][lg * 8];
            bh[i] = *(const short8v*)&Bsh[wc * 64 + i * 16 + l15][lg * 8];
            bl[i] = *(const short8v*)&Bsl[wc * 64 + i * 16 + l15][lg * 8];
        }
#pragma unroll
        for (int mi = 0; mi < 4; ++mi)
#pragma unroll
            for (int ni = 0; ni < 4; ++ni) {
                acc[mi][ni] = __builtin_amdgcn_mfma_f32_16x16x32_bf16(ah[mi], bh[ni], acc[mi][ni], 0, 0, 0);
                acc[mi][ni] = __builtin_amdgcn_mfma_f32_16x16x32_bf16(ah[mi], bl[ni], acc[mi][ni], 0, 0, 0);
                acc[mi][ni] = __builtin_amdgcn_mfma_f32_16x16x32_bf16(al[mi], bh[ni], acc[mi][ni], 0, 0, 0);
            }
    }

    const int head_w = (bn >> 6) + wc;   // blockIdx.y*4 + wc
    float ca[4], cd[4];
#pragma unroll
    for (int ni = 0; ni < 4; ++ni) {
        ca[ni] = a_src[head_w * 64 + ni * 16 + l15];
        cd[ni] = a_dst[head_w * 64 + ni * 16 + l15];
    }
#pragma unroll
    for (int mi = 0; mi < 4; ++mi) {
#pragma unroll
        for (int r = 0; r < 4; ++r) {
            int row = bm + wr * 64 + mi * 16 + lg * 4 + r;
            float ps = 0.f, pd = 0.f;
#pragma unroll
            for (int ni = 0; ni < 4; ++ni) {
                float cv = acc[mi][ni][r];
                int col = bn + wc * 64 + ni * 16 + l15;
                if (row < M) C[(size_t)row * NHF + col] = (_Float16)cv;
                ps += cv * ca[ni];
                pd += cv * cd[ni];
            }
#pragma unroll
            for (int off = 1; off < 16; off <<= 1) {
                ps += __shfl_xor(ps, off);
                pd += __shfl_xor(pd, off);
            }
            if (l15 == 0 && row < M) {
                asrc_out[row * HD + head_w] = ps;
                adst_out[row * HD + head_w] = pd;
            }
        }
    }
}

// ---------------- fused edge softmax + aggregation ----------------
// ONE wave per node: each lane owns 8 contiguous feats (16B h8 load per edge).
// 4-edge batches. Direct exp (max cancels; alphas bounded for this data).
// mode=1: ReLU + write h as bf16 hi/lo (pre-split for GEMM2). mode=0: f32 out.
__global__ __launch_bounds__(256) void k_aggregate(
    const _Float16* __restrict__ xl, const float* __restrict__ asrc,
    const float* __restrict__ adst, const int* __restrict__ row_ptr,
    const int* __restrict__ csr_src, const float* __restrict__ bias,
    float* __restrict__ out, unsigned short* __restrict__ o_hi,
    unsigned short* __restrict__ o_lo, int mode)
{
    __shared__ float sh[4][NHF];
    const int wid  = threadIdx.x >> 6;
    const int lane = threadIdx.x & 63;
    const int n    = blockIdx.x * 4 + wid;   // NN % 4 == 0
    const int head = lane >> 3;
    const int off  = lane * 8;

    const float ad = adst[n * HD + head];
    const int e0 = row_ptr[n];
    const int e1 = row_ptr[n + 1];

    float acc[8] = {};
    float s = 0.f;

    int e = e0;
    for (; e + 4 <= e1; e += 4) {
        int i0 = csr_src[e];
        int i1 = csr_src[e + 1];
        int i2 = csr_src[e + 2];
        int i3 = csr_src[e + 3];
        float a0 = asrc[i0 * HD + head];
        float a1 = asrc[i1 * HD + head];
        float a2 = asrc[i2 * HD + head];
        float a3 = asrc[i3 * HD + head];
        h8 v0 = *(const h8*)(xl + (size_t)i0 * NHF + off);
        h8 v1 = *(const h8*)(xl + (size_t)i1 * NHF + off);
        h8 v2 = *(const h8*)(xl + (size_t)i2 * NHF + off);
        h8 v3 = *(const h8*)(xl + (size_t)i3 * NHF + off);
        a0 += ad; a1 += ad; a2 += ad; a3 += ad;
        float p0 = __expf(a0 > 0.f ? a0 : 0.2f * a0);
        float p1 = __expf(a1 > 0.f ? a1 : 0.2f * a1);
        float p2 = __expf(a2 > 0.f ? a2 : 0.2f * a2);
        float p3 = __expf(a3 > 0.f ? a3 : 0.2f * a3);
        s += p0 + p1 + p2 + p3;
#pragma unroll
        for (int j = 0; j < 8; ++j) {
            acc[j] += p0 * (float)v0[j];
            acc[j] += p1 * (float)v1[j];
            acc[j] += p2 * (float)v2[j];
            acc[j] += p3 * (float)v3[j];
        }
    }
    for (; e < e1; ++e) {
        int i0 = csr_src[e];
        float a = asrc[i0 * HD + head] + ad;
        h8 vv = *(const h8*)(xl + (size_t)i0 * NHF + off);
        float p = __expf(a > 0.f ? a : 0.2f * a);
        s += p;
#pragma unroll
        for (int j = 0; j < 8; ++j) acc[j] += p * (float)vv[j];
    }

    const float inv = 1.f / (s + 1e-16f);
#pragma unroll
    for (int j = 0; j < 8; ++j) sh[wid][off + j] = acc[j] * inv;
    __syncthreads();

    float sum = 0.f;
#pragma unroll
    for (int h2 = 0; h2 < HD; ++h2) sum += sh[wid][h2 * CD + lane];
    float res = sum * 0.125f + bias[lane];
    if (mode) {
        res = fmaxf(res, 0.f);
        unsigned short hb = f32_to_bf16(res);
        o_hi[(size_t)n * CD + lane] = hb;
        o_lo[(size_t)n * CD + lane] = f32_to_bf16(res - bf16_to_f32(hb));
    } else {
        out[(size_t)n * CD + lane] = res;
    }
}

// ---------------- launch ----------------
extern "C" void kernel_launch(void* const* d_in, const int* in_sizes, int n_in,
                              void* d_out, int out_size, void* d_ws, size_t ws_size,
                              hipStream_t stream) {
    const float* x   = (const float*)d_in[0];
    const int*   ei  = (const int*)d_in[1];
    const float* W1  = (const float*)d_in[2];
    const float* as1 = (const float*)d_in[3];
    const float* ad1 = (const float*)d_in[4];
    const float* b1  = (const float*)d_in[5];
    const float* W2  = (const float*)d_in[6];
    const float* as2 = (const float*)d_in[7];
    const float* ad2 = (const float*)d_in[8];
    const float* b2  = (const float*)d_in[9];

    const int E = in_sizes[1] / 2;      // 800000
    const int* esrc = ei;
    const int* edst = ei + E;

    char* ws = (char*)d_ws;
    _Float16* xlh        = (_Float16*)ws;                      // 51,200,000
    float* asrc          = (float*)(ws + 51200000);            // 1,600,000
    float* adst          = (float*)(ws + 52800000);            // 1,600,000
    unsigned short* Hh   = (unsigned short*)(ws + 54400000);   // 6,406,144 (MPAD*64*2)
    unsigned short* Hl   = (unsigned short*)(ws + 60806144);   // 6,406,144
    int*   row_ptr       = (int*)(ws + 67212288);              // 200,004
    int*   cursor        = (int*)(ws + 67412480);              // 200,000
    int*   csr_src       = (int*)(ws + 67612480);              // 3,400,000
    unsigned short* Bht1 = (unsigned short*)(ws + 71012480);   // 262,144
    unsigned short* Blt1 = (unsigned short*)(ws + 71274624);   // 262,144
    unsigned short* Bht2 = (unsigned short*)(ws + 71536768);   // 65,536
    unsigned short* Blt2 = (unsigned short*)(ws + 71602304);   // 65,536
    int*   bsums         = (int*)(ws + 71667840);              // 784
    int*   boffs         = (int*)(ws + 71668736);              // 784

    // CSR build (shared by both layers)
    k_init_cnt<<<(NN + 255) / 256, 256, 0, stream>>>(cursor);
    k_hist<<<(E + 255) / 256, 256, 0, stream>>>(edst, E, cursor);
    k_block_sums<<<NBLK, SCAN_B, 0, stream>>>(cursor, bsums);
    k_scan_bsums<<<1, SCAN_B, 0, stream>>>(bsums, boffs, NBLK);
    k_emit<<<NBLK, SCAN_B, 0, stream>>>(cursor, boffs, row_ptr, cursor, csr_src);
    k_scatter<<<(E + 255) / 256, 256, 0, stream>>>(esrc, edst, E, cursor, csr_src);

    // weight splits (tiny)
    k_split_bt<<<(256 * NHF + 255) / 256, 256, 0, stream>>>(W1, Bht1, Blt1, 256);
    k_split_bt<<<(64 * NHF + 255) / 256, 256, 0, stream>>>(W2, Bht2, Blt2, 64);

    dim3 gemm_grid(MPAD / BM, NHF / BN);   // (391, 2)

    // layer 1: A = x (f32, split on stage)
    k_gemm<1><<<gemm_grid, 512, 0, stream>>>(x, nullptr, nullptr, Bht1, Blt1, as1, ad1,
                                             xlh, asrc, adst, NN, 256);
    k_aggregate<<<NN / 4, 256, 0, stream>>>(xlh, asrc, adst, row_ptr, csr_src, b1,
                                            nullptr, Hh, Hl, 1);

    // layer 2: A = h (pre-split bf16 hi/lo, written by aggregate-1)
    k_gemm<0><<<gemm_grid, 512, 0, stream>>>(nullptr, Hh, Hl, Bht2, Blt2, as2, ad2,
                                             xlh, asrc, adst, NN, 64);
    k_aggregate<<<NN / 4, 256, 0, stream>>>(xlh, asrc, adst, row_ptr, csr_src, b2,
                                            (float*)d_out, nullptr, nullptr, 0);
}